// Round 10
// baseline (254.095 us; speedup 1.0000x reference)
//
#include <hip/hip_runtime.h>
#include <hip/hip_bf16.h>

// LinearAttention: B=4 N=4096 D=1024 H=16 DH=64
// Pipeline:
//  1. prep: convert x -> bf16, transpose-convert Wq/Wk/Wv -> Wt (B^T), Wo -> WoT,
//     zero ksum + kvf accumulators
//  2. gemm128<0>: qkv = x @ [Wq|Wk|Wv]  (128x128, 2-phase, 16x16x32 MFMA, swizzled LDS),
//     elu+1 on q,k; LDS-staged epilogue: q -> [bh][n][d], k,v -> [bh][d][n]; fused ksum atomics
//  3. kv: 8-way n-split partial kv^T, atomicAdd fp32 into kvf[bh][e][d] (no combine kernel)
//  4. attn = (q @ kv) / (q . ksum + eps)  -- kvf staged fp32->bf16 in swizzled LDS
//  5. gemm128<1>: out = attn @ Wo + bo

#define DEV_INLINE __device__ __forceinline__

typedef short bf16x8 __attribute__((ext_vector_type(8)));
typedef float f32x4  __attribute__((ext_vector_type(4)));

static constexpr int Bb = 4, Nn = 4096, Dd = 1024, Hh = 16, DHd = 64;
static constexpr int Mrows = Bb * Nn;   // 16384

DEV_INLINE float bf2f(short s) {
  unsigned u = ((unsigned)(unsigned short)s) << 16;
  float f; __builtin_memcpy(&f, &u, 4); return f;
}
DEV_INLINE short f2bf(float f) {
  unsigned u; __builtin_memcpy(&u, &f, 4);
  unsigned r = (u + 0x7fffu + ((u >> 16) & 1u)) >> 16;
  return (short)r;
}

DEV_INLINE void gload16(const void* g, void* l) {
  typedef __attribute__((address_space(1))) const void gv_t;
  typedef __attribute__((address_space(3))) void lv_t;
  __builtin_amdgcn_global_load_lds((gv_t*)g, (lv_t*)l, 16, 0, 0);
}

// swizzled LDS offset (shorts) for the 128x128 bf16 epilogue tile
DEV_INLINE int lds_off(int r_, int c_) {
  return r_ * 128 + ((((c_ >> 3) ^ (r_ & 7)) << 3) | (c_ & 7));
}

// ---------------- 1. prep: x-convert + W transposes + accumulator zero ----------------
// grid (64,16,5): z<4 & x<16 -> W transpose slice z; z==4 -> x-convert (1024 blocks)
__global__ void prep_kernel(const float* __restrict__ x,
                            const float* __restrict__ Wq, const float* __restrict__ Wk,
                            const float* __restrict__ Wv, const float* __restrict__ Wo,
                            short* __restrict__ xb, short* __restrict__ Wt,
                            short* __restrict__ WoT, float* __restrict__ ksum,
                            float* __restrict__ kvf) {
  int z = blockIdx.z;
  int t = threadIdx.x;
  if (z == 4) {
    int bid = blockIdx.y * 64 + blockIdx.x;         // 0..1023
    const int total = Mrows * 1024 / 4;
    for (int i = bid * 256 + t; i < total; i += 1024 * 256) {
      float4 v = ((const float4*)x)[i];
      short4 o;
      o.x = f2bf(v.x); o.y = f2bf(v.y); o.z = f2bf(v.z); o.w = f2bf(v.w);
      ((short4*)xb)[i] = o;
    }
    return;
  }
  if (blockIdx.x >= 16) return;
  if (z == 0 && blockIdx.y == 0)
    ksum[blockIdx.x * 256 + t] = 0.f;               // 64*64 floats
  if (z == 1 && blockIdx.y == 0) {
    // zero kvf: 64*4096 floats, 16 blocks x 256 threads x 16 float4
    float4* p = (float4*)kvf;
    int base = (blockIdx.x * 256 + t) * 16;
    for (int j = 0; j < 16; ++j) p[base + j] = make_float4(0.f, 0.f, 0.f, 0.f);
  }
  const float* W = (z == 0) ? Wq : (z == 1) ? Wk : (z == 2) ? Wv : Wo;
  short* dstb = (z < 3) ? (Wt + (size_t)z * 1024 * 1024) : WoT;
  __shared__ float tile[64][69];
  int r = t >> 2, c4 = (t & 3) << 4;
  const float* src = W + (blockIdx.y * 64 + r) * 1024 + blockIdx.x * 64 + c4;
  for (int j = 0; j < 4; ++j) {
    float4 v = ((const float4*)src)[j];
    tile[r][c4 + 4 * j + 0] = v.x;
    tile[r][c4 + 4 * j + 1] = v.y;
    tile[r][c4 + 4 * j + 2] = v.z;
    tile[r][c4 + 4 * j + 3] = v.w;
  }
  __syncthreads();
  __attribute__((aligned(16))) short tmp[16];
  for (int j = 0; j < 16; ++j) tmp[j] = f2bf(tile[c4 + j][r]);
  short* dst = dstb + (blockIdx.x * 64 + r) * 1024 + blockIdx.y * 64 + c4;
  ((int4*)dst)[0] = ((int4*)tmp)[0];
  ((int4*)dst)[1] = ((int4*)tmp)[1];
}

// ---------------- 2/5. 128x128 bf16 MFMA GEMM (2-phase, 16x16x32) ----------------
// XCD-contiguous mapping; K-loop LDS XOR-swizzled (linear gload_lds dest +
// pre-swizzled global source slot + same XOR on ds_read).
template <int MODE>
__global__ __launch_bounds__(256, 4) void gemm128_kernel(
    const short* __restrict__ A, const short* __restrict__ Bt,
    short* __restrict__ q, short* __restrict__ kT, short* __restrict__ vT,
    float* __restrict__ out, const float* __restrict__ bias,
    float* __restrict__ ksum, int nTilesN) {
  __shared__ __align__(16) short sm[128 * 128];   // K-loop: A | B halves; epilogue: C tile
  short* smA = sm;
  short* smB = sm + 8192;
  const int K = 1024;
  int bid0 = blockIdx.x;
  int xcd = bid0 & 7, local = bid0 >> 3;
  int chunk = local >> 6, rem = local & 63;       // 64 blocks per 8x8 chunk
  int ncc = nTilesN >> 3;
  int cm = chunk / ncc, cn = chunk % ncc;
  int tm = xcd * 16 + cm * 8 + (rem >> 3);
  int tn = cn * 8 + (rem & 7);

  int t = threadIdx.x, w = t >> 6, lane = t & 63;
  int rl = lane & 15, kg = lane >> 4;
  int wr = w >> 1, wc = w & 1;
  const short* Abase = A + (size_t)tm * 128 * K;
  const short* Bbase = Bt + (size_t)tn * 128 * K;

  f32x4 acc[4][4] = {};
  for (int k0 = 0; k0 < K; k0 += 64) {
    __syncthreads();
    for (int p = 0; p < 4; ++p) {
      int c = p * 256 + t;
      int row = c >> 3, u = c & 7;
      int off = ((u ^ (row & 7)) << 3);           // pre-swizzled source slot
      gload16(Abase + row * K + k0 + off, (char*)smA + p * 4096 + w * 1024);
      gload16(Bbase + row * K + k0 + off, (char*)smB + p * 4096 + w * 1024);
    }
    __syncthreads();
    for (int kk = 0; kk < 2; ++kk) {
      int slot = kk * 4 + kg;                     // kb>>3
      bf16x8 af[4], bfr[4];
      for (int mt = 0; mt < 4; ++mt) {
        int row = wr * 64 + mt * 16 + rl;
        af[mt] = *(const bf16x8*)&smA[row * 64 + ((slot ^ (row & 7)) << 3)];
      }
      for (int nt = 0; nt < 4; ++nt) {
        int row = wc * 64 + nt * 16 + rl;
        bfr[nt] = *(const bf16x8*)&smB[row * 64 + ((slot ^ (row & 7)) << 3)];
      }
      for (int mt = 0; mt < 4; ++mt)
        for (int nt = 0; nt < 4; ++nt)
          acc[mt][nt] = __builtin_amdgcn_mfma_f32_16x16x32_bf16(af[mt], bfr[nt], acc[mt][nt], 0, 0, 0);
    }
  }
  // C/D layout: col = lane&15, row = 4*(lane>>4)+reg
  if (MODE == 1) {
    // LDS-staged fp32 epilogue, two 64-row half-passes, coalesced float4 stores
    float* smf = (float*)sm;                      // 64 x 128 fp32 = 32 KB
    __syncthreads();
    for (int h = 0; h < 2; ++h) {
      if (wr == h) {
        for (int mt = 0; mt < 4; ++mt)
          for (int nt = 0; nt < 4; ++nt)
            for (int r = 0; r < 4; ++r)
              smf[(mt * 16 + kg * 4 + r) * 128 + wc * 64 + nt * 16 + rl] = acc[mt][nt][r];
      }
      __syncthreads();
      for (int i = 0; i < 8; ++i) {
        int idx = i * 256 + t;
        int row = idx >> 5, c4 = (idx & 31) << 2;
        float4 v = *(const float4*)&smf[row * 128 + c4];
        float4 bv = *(const float4*)&bias[tn * 128 + c4];
        v.x += bv.x; v.y += bv.y; v.z += bv.z; v.w += bv.w;
        *(float4*)&out[(size_t)(tm * 128 + h * 64 + row) * Dd + tn * 128 + c4] = v;
      }
      __syncthreads();
    }
    return;
  }
  // MODE 0: stage C tile in LDS (transposed for k/v), then coalesced int4 stores
  __syncthreads();
  int sec = tn >> 3;                     // 0=q 1=k 2=v (128-col tiles never straddle)
  int tloc = tn & 7;
  for (int mt = 0; mt < 4; ++mt)
    for (int nt = 0; nt < 4; ++nt)
      for (int r = 0; r < 4; ++r) {
        float v = acc[mt][nt][r];
        if (sec <= 1) v = v > 0.f ? v + 1.f : __expf(v);   // elu(x)+1
        int row = wr * 64 + mt * 16 + kg * 4 + r;
        int col = wc * 64 + nt * 16 + rl;
        int o = (sec == 0) ? lds_off(row, col) : lds_off(col, row);
        sm[o] = f2bf(v);
      }
  __syncthreads();
  if (sec == 0) {
    for (int i = 0; i < 8; ++i) {
      int idx = i * 256 + t;
      int row = idx >> 4, c = idx & 15;
      int col0 = c * 8;
      int gcol = tloc * 128 + col0;
      int h = gcol >> 6, d0 = gcol & 63;
      int grow = tm * 128 + row;
      int b = grow >> 12, n = grow & 4095;
      *(int4*)&q[(((size_t)(b * Hh + h)) * Nn + n) * DHd + d0] = *(const int4*)&sm[lds_off(row, col0)];
    }
  } else {
    short* dst = (sec == 1) ? kT : vT;
    for (int i = 0; i < 8; ++i) {
      int idx = i * 256 + t;
      int dcol = idx >> 4, c = idx & 15;
      int n0 = c * 8;
      int gcol = tloc * 128 + dcol;
      int h = gcol >> 6, d = gcol & 63;
      int grow0 = tm * 128 + n0;
      int b = grow0 >> 12, n = grow0 & 4095;
      *(int4*)&dst[(((size_t)(b * Hh + h)) * DHd + d) * Nn + n] = *(const int4*)&sm[lds_off(dcol, n0)];
    }
    if (sec == 1) {
      // fused ksum: sum the staged k-tile (layout [dcol][n], swizzled) over n
      int dcol = t >> 1, half = t & 1;
      float s = 0.f;
      for (int c = half * 64; c < half * 64 + 64; ++c)
        s += bf2f(sm[lds_off(dcol, c)]);
      s += __shfl_xor(s, 1);
      if (half == 0) {
        int g = tloc * 128 + dcol;
        int h = g >> 6, d = g & 63;
        int b = (tm * 128) >> 12;
        atomicAdd(&ksum[(b * Hh + h) * DHd + d], s);
      }
    }
  }
}

// ---------------- 3. kv partials -> atomicAdd into kvf[bh][e][d] fp32 ----------------
__global__ __launch_bounds__(256, 2) void kv_kernel(const short* __restrict__ kT,
                                                    const short* __restrict__ vT,
                                                    float* __restrict__ kvf) {
  __shared__ __align__(16) short smK[64 * 128];
  __shared__ __align__(16) short smV[64 * 128];
  int bh = blockIdx.x, seg = blockIdx.y;
  int t = threadIdx.x;
  int w = t >> 6, lane = t & 63, rl = lane & 15, kg = lane >> 4;
  const short* kb = kT + (size_t)bh * DHd * Nn + seg * 512;
  const short* vb = vT + (size_t)bh * DHd * Nn + seg * 512;
  f32x4 acc[4] = {};
  for (int n0 = 0; n0 < 512; n0 += 128) {
    __syncthreads();
    for (int p = 0; p < 4; ++p) {
      int c = p * 256 + t;
      int row = c >> 4, u = c & 15;
      int off = ((u ^ (row & 15)) << 3);          // pre-swizzled source slot
      gload16(kb + row * Nn + n0 + off, (char*)smK + p * 4096 + w * 1024);
      gload16(vb + row * Nn + n0 + off, (char*)smV + p * 4096 + w * 1024);
    }
    __syncthreads();
    for (int kk = 0; kk < 4; ++kk) {
      int slot = kk * 4 + kg;
      int rowA = w * 16 + rl;
      bf16x8 av = *(const bf16x8*)&smK[rowA * 128 + ((slot ^ (rowA & 15)) << 3)];
      for (int nt = 0; nt < 4; ++nt) {
        int rowB = nt * 16 + rl;
        bf16x8 bv = *(const bf16x8*)&smV[rowB * 128 + ((slot ^ (rowB & 15)) << 3)];
        acc[nt] = __builtin_amdgcn_mfma_f32_16x16x32_bf16(av, bv, acc[nt], 0, 0, 0);
      }
    }
  }
  // stage 64x64 fp32 tile in LDS, then coalesced atomicAdd into kvf
  float* smf = (float*)smK;
  __syncthreads();
  for (int nt = 0; nt < 4; ++nt)
    for (int r = 0; r < 4; ++r)
      smf[(nt * 16 + rl) * 64 + (w * 16 + kg * 4 + r)] = acc[nt][r];
  __syncthreads();
  float* dst = kvf + (size_t)bh * 4096;
  for (int i = 0; i < 4; ++i) {
    int idx = i * 1024 + t * 4;
    atomicAdd(&dst[idx + 0], smf[idx + 0]);
    atomicAdd(&dst[idx + 1], smf[idx + 1]);
    atomicAdd(&dst[idx + 2], smf[idx + 2]);
    atomicAdd(&dst[idx + 3], smf[idx + 3]);
  }
}

// ---------------- 4. out = (q @ kv) / z ----------------
__global__ __launch_bounds__(256, 4) void attn_kernel(const short* __restrict__ q,
                                                      const float* __restrict__ kvf,
                                                      const float* __restrict__ ksum,
                                                      short* __restrict__ attn) {
  int rb = blockIdx.x, bh = blockIdx.y;
  int b = bh >> 4, h = bh & 15;
  __shared__ float sks[64];
  __shared__ __align__(16) short skv[64 * 64];    // kv tile, XOR-swizzled bf16
  __shared__ __align__(16) short satt[64 * 64];
  int t = threadIdx.x, w = t >> 6, lane = t & 63, rl = lane & 15, kg = lane >> 4;
  if (t < 64) sks[t] = ksum[bh * 64 + t];
  // stage kvf (fp32, [e][d]) -> swizzled bf16 LDS
  {
    const float* kvb = kvf + (size_t)bh * 4096;
    for (int i = 0; i < 4; ++i) {
      int idx = i * 1024 + t * 4;
      float4 v = *(const float4*)&kvb[idx];
      int e = idx >> 6, c = idx & 63;
      short4 o;
      o.x = f2bf(v.x); o.y = f2bf(v.y); o.z = f2bf(v.z); o.w = f2bf(v.w);
      *(short4*)&skv[e * 64 + (((c >> 3) ^ (e & 7)) << 3) + (c & 7)] = o;
    }
  }
  __syncthreads();
  int row0 = rb * 64 + w * 16;
  const short* qb = q + ((size_t)bh * Nn + row0) * DHd;
  f32x4 acc[4] = {};
  float zp = 0.f;
  for (int kk = 0; kk < 2; ++kk) {
    int kb = kk * 32 + kg * 8;
    int slot = kk * 4 + kg;
    bf16x8 av = *(const bf16x8*)&qb[rl * DHd + kb];
    for (int jj = 0; jj < 8; ++jj) zp += bf2f(av[jj]) * sks[kb + jj];
    for (int nt = 0; nt < 4; ++nt) {
      int row = nt * 16 + rl;
      bf16x8 bfr = *(const bf16x8*)&skv[row * 64 + ((slot ^ (row & 7)) << 3)];
      acc[nt] = __builtin_amdgcn_mfma_f32_16x16x32_bf16(av, bfr, acc[nt], 0, 0, 0);
    }
  }
  zp += __shfl_xor(zp, 16);
  zp += __shfl_xor(zp, 32);     // every lane now holds z for row (lane&15)
  float zr[4];
  for (int r = 0; r < 4; ++r) zr[r] = __shfl(zp, kg * 4 + r);
  for (int nt = 0; nt < 4; ++nt)
    for (int r = 0; r < 4; ++r)
      satt[(w * 16 + kg * 4 + r) * 64 + nt * 16 + rl] = f2bf(acc[nt][r] / (zr[r] + 1e-6f));
  __syncthreads();
  for (int i = 0; i < 2; ++i) {
    int idx = i * 256 + t;                 // int4 index over 64x64 shorts
    int row = idx >> 3, c8 = (idx & 7) << 3;
    int n = rb * 64 + row;
    *(int4*)&attn[((size_t)(b * Nn + n)) * 1024 + h * 64 + c8] = *(const int4*)&satt[row * 64 + c8];
  }
}

// ---------------- launch ----------------
extern "C" void kernel_launch(void* const* d_in, const int* in_sizes, int n_in,
                              void* d_out, int out_size, void* d_ws, size_t ws_size,
                              hipStream_t stream) {
  const float* x  = (const float*)d_in[0];
  const float* Wq = (const float*)d_in[1];
  const float* Wk = (const float*)d_in[2];
  const float* Wv = (const float*)d_in[3];
  const float* Wo = (const float*)d_in[4];
  const float* bo = (const float*)d_in[5];
  float* out = (float*)d_out;

  char* ws = (char*)d_ws;
  size_t off = 0;
  auto alloc = [&](size_t bytes) {
    char* p = ws + off;
    off += (bytes + 255) & ~(size_t)255;
    return p;
  };
  short* xb   = (short*)alloc((size_t)Mrows * 1024 * 2);     // 32 MB
  short* Wt   = (short*)alloc((size_t)3072 * 1024 * 2);      // 6 MB
  short* WoT  = (short*)alloc((size_t)1024 * 1024 * 2);      // 2 MB
  short* qb   = (short*)alloc((size_t)64 * Nn * DHd * 2);    // 32 MB  [bh][n][d]
  short* kT   = (short*)alloc((size_t)64 * DHd * Nn * 2);    // 32 MB  [bh][d][n]
  short* vT   = (short*)alloc((size_t)64 * DHd * Nn * 2);    // 32 MB  [bh][d][n]
  float* ksum = (float*)alloc((size_t)64 * 64 * 4);          // fused ksum accumulator
  float* kvf  = (float*)alloc((size_t)64 * 4096 * 4);        // 1 MB kv fp32 accumulator
  short* attn = (short*)alloc((size_t)Mrows * 1024 * 2);     // 32 MB

  prep_kernel<<<dim3(64, 16, 5), 256, 0, stream>>>(x, Wq, Wk, Wv, Wo, xb, Wt, WoT, ksum, kvf);

  gemm128_kernel<0><<<3072, 256, 0, stream>>>(xb, Wt, qb, kT, vT, nullptr, nullptr, ksum, 24);
  kv_kernel<<<dim3(64, 8), 256, 0, stream>>>(kT, vT, kvf);
  attn_kernel<<<dim3(64, 64), 256, 0, stream>>>(qb, kvf, ksum, attn);
  gemm128_kernel<1><<<1024, 256, 0, stream>>>(attn, WoT, nullptr, nullptr, nullptr, out, bo, nullptr, 8);
}

// Round 11
// 237.545 us; speedup vs baseline: 1.0697x; 1.0697x over previous
//
#include <hip/hip_runtime.h>
#include <hip/hip_bf16.h>

// LinearAttention: B=4 N=4096 D=1024 H=16 DH=64
// Best-measured configuration (r4 structure, merged prep):
//  1. prep: convert x -> bf16, transpose-convert Wq/Wk/Wv -> Wt (B^T), Wo -> WoT, zero ksum
//  2. gemm128<0>: qkv = x @ [Wq|Wk|Wv]  (128x128, 2-phase, 16x16x32 MFMA, swizzled LDS),
//     elu+1 on q,k; LDS-staged epilogue: q -> [bh][n][d], k,v -> [bh][d][n]; fused ksum atomics
//  3. kv partials (8-way n-split, fp32, LDS-staged out) + kvc combine -> kvT bf16
//  4. attn = (q @ kv) / (q . ksum + eps), LDS-staged coalesced out
//  5. gemm128<1>: out = attn @ Wo + bo (fp32, LDS-staged coalesced epilogue)

#define DEV_INLINE __device__ __forceinline__

typedef short bf16x8 __attribute__((ext_vector_type(8)));
typedef float f32x4  __attribute__((ext_vector_type(4)));

static constexpr int Bb = 4, Nn = 4096, Dd = 1024, Hh = 16, DHd = 64;
static constexpr int Mrows = Bb * Nn;   // 16384

DEV_INLINE float bf2f(short s) {
  unsigned u = ((unsigned)(unsigned short)s) << 16;
  float f; __builtin_memcpy(&f, &u, 4); return f;
}
DEV_INLINE short f2bf(float f) {
  unsigned u; __builtin_memcpy(&u, &f, 4);
  unsigned r = (u + 0x7fffu + ((u >> 16) & 1u)) >> 16;
  return (short)r;
}

DEV_INLINE void gload16(const void* g, void* l) {
  typedef __attribute__((address_space(1))) const void gv_t;
  typedef __attribute__((address_space(3))) void lv_t;
  __builtin_amdgcn_global_load_lds((gv_t*)g, (lv_t*)l, 16, 0, 0);
}

// swizzled LDS offset (shorts) for the 128x128 bf16 epilogue tile
DEV_INLINE int lds_off(int r_, int c_) {
  return r_ * 128 + ((((c_ >> 3) ^ (r_ & 7)) << 3) | (c_ & 7));
}

// ---------------- 1. prep: x-convert + W transposes + ksum zero ----------------
// grid (64,16,5): z<4 & x<16 -> W transpose slice z; z==4 -> x-convert (1024 blocks)
__global__ void prep_kernel(const float* __restrict__ x,
                            const float* __restrict__ Wq, const float* __restrict__ Wk,
                            const float* __restrict__ Wv, const float* __restrict__ Wo,
                            short* __restrict__ xb, short* __restrict__ Wt,
                            short* __restrict__ WoT, float* __restrict__ ksum) {
  int z = blockIdx.z;
  int t = threadIdx.x;
  if (z == 4) {
    int bid = blockIdx.y * 64 + blockIdx.x;         // 0..1023
    const int total = Mrows * 1024 / 4;
    for (int i = bid * 256 + t; i < total; i += 1024 * 256) {
      float4 v = ((const float4*)x)[i];
      short4 o;
      o.x = f2bf(v.x); o.y = f2bf(v.y); o.z = f2bf(v.z); o.w = f2bf(v.w);
      ((short4*)xb)[i] = o;
    }
    return;
  }
  if (blockIdx.x >= 16) return;
  if (z == 0 && blockIdx.y == 0)
    ksum[blockIdx.x * 256 + t] = 0.f;               // 64*64 floats
  const float* W = (z == 0) ? Wq : (z == 1) ? Wk : (z == 2) ? Wv : Wo;
  short* dstb = (z < 3) ? (Wt + (size_t)z * 1024 * 1024) : WoT;
  __shared__ float tile[64][69];
  int r = t >> 2, c4 = (t & 3) << 4;
  const float* src = W + (blockIdx.y * 64 + r) * 1024 + blockIdx.x * 64 + c4;
  for (int j = 0; j < 4; ++j) {
    float4 v = ((const float4*)src)[j];
    tile[r][c4 + 4 * j + 0] = v.x;
    tile[r][c4 + 4 * j + 1] = v.y;
    tile[r][c4 + 4 * j + 2] = v.z;
    tile[r][c4 + 4 * j + 3] = v.w;
  }
  __syncthreads();
  __attribute__((aligned(16))) short tmp[16];
  for (int j = 0; j < 16; ++j) tmp[j] = f2bf(tile[c4 + j][r]);
  short* dst = dstb + (blockIdx.x * 64 + r) * 1024 + blockIdx.y * 64 + c4;
  ((int4*)dst)[0] = ((int4*)tmp)[0];
  ((int4*)dst)[1] = ((int4*)tmp)[1];
}

// ---------------- 2/5. 128x128 bf16 MFMA GEMM (2-phase, 16x16x32) ----------------
// XCD-contiguous mapping; K-loop LDS XOR-swizzled (linear gload_lds dest +
// pre-swizzled global source slot + same XOR on ds_read).
template <int MODE>
__global__ __launch_bounds__(256, 4) void gemm128_kernel(
    const short* __restrict__ A, const short* __restrict__ Bt,
    short* __restrict__ q, short* __restrict__ kT, short* __restrict__ vT,
    float* __restrict__ out, const float* __restrict__ bias,
    float* __restrict__ ksum, int nTilesN) {
  __shared__ __align__(16) short sm[128 * 128];   // K-loop: A | B halves; epilogue: C tile
  short* smA = sm;
  short* smB = sm + 8192;
  const int K = 1024;
  int bid0 = blockIdx.x;
  int xcd = bid0 & 7, local = bid0 >> 3;
  int chunk = local >> 6, rem = local & 63;       // 64 blocks per 8x8 chunk
  int ncc = nTilesN >> 3;
  int cm = chunk / ncc, cn = chunk % ncc;
  int tm = xcd * 16 + cm * 8 + (rem >> 3);
  int tn = cn * 8 + (rem & 7);

  int t = threadIdx.x, w = t >> 6, lane = t & 63;
  int rl = lane & 15, kg = lane >> 4;
  int wr = w >> 1, wc = w & 1;
  const short* Abase = A + (size_t)tm * 128 * K;
  const short* Bbase = Bt + (size_t)tn * 128 * K;

  f32x4 acc[4][4] = {};
  for (int k0 = 0; k0 < K; k0 += 64) {
    __syncthreads();
    for (int p = 0; p < 4; ++p) {
      int c = p * 256 + t;
      int row = c >> 3, u = c & 7;
      int off = ((u ^ (row & 7)) << 3);           // pre-swizzled source slot
      gload16(Abase + row * K + k0 + off, (char*)smA + p * 4096 + w * 1024);
      gload16(Bbase + row * K + k0 + off, (char*)smB + p * 4096 + w * 1024);
    }
    __syncthreads();
    for (int kk = 0; kk < 2; ++kk) {
      int slot = kk * 4 + kg;                     // kb>>3
      bf16x8 af[4], bfr[4];
      for (int mt = 0; mt < 4; ++mt) {
        int row = wr * 64 + mt * 16 + rl;
        af[mt] = *(const bf16x8*)&smA[row * 64 + ((slot ^ (row & 7)) << 3)];
      }
      for (int nt = 0; nt < 4; ++nt) {
        int row = wc * 64 + nt * 16 + rl;
        bfr[nt] = *(const bf16x8*)&smB[row * 64 + ((slot ^ (row & 7)) << 3)];
      }
      for (int mt = 0; mt < 4; ++mt)
        for (int nt = 0; nt < 4; ++nt)
          acc[mt][nt] = __builtin_amdgcn_mfma_f32_16x16x32_bf16(af[mt], bfr[nt], acc[mt][nt], 0, 0, 0);
    }
  }
  // C/D layout: col = lane&15, row = 4*(lane>>4)+reg
  if (MODE == 1) {
    // LDS-staged fp32 epilogue, two 64-row half-passes, coalesced float4 stores
    float* smf = (float*)sm;                      // 64 x 128 fp32 = 32 KB
    __syncthreads();
    for (int h = 0; h < 2; ++h) {
      if (wr == h) {
        for (int mt = 0; mt < 4; ++mt)
          for (int nt = 0; nt < 4; ++nt)
            for (int r = 0; r < 4; ++r)
              smf[(mt * 16 + kg * 4 + r) * 128 + wc * 64 + nt * 16 + rl] = acc[mt][nt][r];
      }
      __syncthreads();
      for (int i = 0; i < 8; ++i) {
        int idx = i * 256 + t;
        int row = idx >> 5, c4 = (idx & 31) << 2;
        float4 v = *(const float4*)&smf[row * 128 + c4];
        float4 bv = *(const float4*)&bias[tn * 128 + c4];
        v.x += bv.x; v.y += bv.y; v.z += bv.z; v.w += bv.w;
        *(float4*)&out[(size_t)(tm * 128 + h * 64 + row) * Dd + tn * 128 + c4] = v;
      }
      __syncthreads();
    }
    return;
  }
  // MODE 0: stage C tile in LDS (transposed for k/v), then coalesced int4 stores
  __syncthreads();
  int sec = tn >> 3;                     // 0=q 1=k 2=v (128-col tiles never straddle)
  int tloc = tn & 7;
  for (int mt = 0; mt < 4; ++mt)
    for (int nt = 0; nt < 4; ++nt)
      for (int r = 0; r < 4; ++r) {
        float v = acc[mt][nt][r];
        if (sec <= 1) v = v > 0.f ? v + 1.f : __expf(v);   // elu(x)+1
        int row = wr * 64 + mt * 16 + kg * 4 + r;
        int col = wc * 64 + nt * 16 + rl;
        int o = (sec == 0) ? lds_off(row, col) : lds_off(col, row);
        sm[o] = f2bf(v);
      }
  __syncthreads();
  if (sec == 0) {
    for (int i = 0; i < 8; ++i) {
      int idx = i * 256 + t;
      int row = idx >> 4, c = idx & 15;
      int col0 = c * 8;
      int gcol = tloc * 128 + col0;
      int h = gcol >> 6, d0 = gcol & 63;
      int grow = tm * 128 + row;
      int b = grow >> 12, n = grow & 4095;
      *(int4*)&q[(((size_t)(b * Hh + h)) * Nn + n) * DHd + d0] = *(const int4*)&sm[lds_off(row, col0)];
    }
  } else {
    short* dst = (sec == 1) ? kT : vT;
    for (int i = 0; i < 8; ++i) {
      int idx = i * 256 + t;
      int dcol = idx >> 4, c = idx & 15;
      int n0 = c * 8;
      int gcol = tloc * 128 + dcol;
      int h = gcol >> 6, d = gcol & 63;
      int grow0 = tm * 128 + n0;
      int b = grow0 >> 12, n = grow0 & 4095;
      *(int4*)&dst[(((size_t)(b * Hh + h)) * DHd + d) * Nn + n] = *(const int4*)&sm[lds_off(dcol, n0)];
    }
    if (sec == 1) {
      // fused ksum: sum the staged k-tile (layout [dcol][n], swizzled) over n
      int dcol = t >> 1, half = t & 1;
      float s = 0.f;
      for (int c = half * 64; c < half * 64 + 64; ++c)
        s += bf2f(sm[lds_off(dcol, c)]);
      s += __shfl_xor(s, 1);
      if (half == 0) {
        int g = tloc * 128 + dcol;
        int h = g >> 6, d = g & 63;
        int b = (tm * 128) >> 12;
        atomicAdd(&ksum[(b * Hh + h) * DHd + d], s);
      }
    }
  }
}

// ---------------- 3. kv partials: kvp[bh][8][e][d] fp32 ----------------
__global__ __launch_bounds__(256, 2) void kv_kernel(const short* __restrict__ kT,
                                                    const short* __restrict__ vT,
                                                    float* __restrict__ kvp) {
  __shared__ __align__(16) short smK[64 * 128];
  __shared__ __align__(16) short smV[64 * 128];
  int bh = blockIdx.x, seg = blockIdx.y;
  int t = threadIdx.x;
  int w = t >> 6, lane = t & 63, rl = lane & 15, kg = lane >> 4;
  const short* kb = kT + (size_t)bh * DHd * Nn + seg * 512;
  const short* vb = vT + (size_t)bh * DHd * Nn + seg * 512;
  f32x4 acc[4] = {};
  for (int n0 = 0; n0 < 512; n0 += 128) {
    __syncthreads();
    for (int p = 0; p < 4; ++p) {
      int c = p * 256 + t;
      int row = c >> 4, u = c & 15;
      int off = ((u ^ (row & 15)) << 3);          // pre-swizzled source slot
      gload16(kb + row * Nn + n0 + off, (char*)smK + p * 4096 + w * 1024);
      gload16(vb + row * Nn + n0 + off, (char*)smV + p * 4096 + w * 1024);
    }
    __syncthreads();
    for (int kk = 0; kk < 4; ++kk) {
      int slot = kk * 4 + kg;
      int rowA = w * 16 + rl;
      bf16x8 av = *(const bf16x8*)&smK[rowA * 128 + ((slot ^ (rowA & 15)) << 3)];
      for (int nt = 0; nt < 4; ++nt) {
        int rowB = nt * 16 + rl;
        bf16x8 bv = *(const bf16x8*)&smV[rowB * 128 + ((slot ^ (rowB & 15)) << 3)];
        acc[nt] = __builtin_amdgcn_mfma_f32_16x16x32_bf16(av, bv, acc[nt], 0, 0, 0);
      }
    }
  }
  // LDS-staged coalesced fp32 output (64x64 tile = 16 KB, reuse smK)
  float* smf = (float*)smK;
  __syncthreads();
  for (int nt = 0; nt < 4; ++nt)
    for (int r = 0; r < 4; ++r)
      smf[(nt * 16 + rl) * 64 + (w * 16 + kg * 4 + r)] = acc[nt][r];
  __syncthreads();
  float* dst = kvp + ((size_t)(bh * 8 + seg)) * 4096;
  for (int i = 0; i < 4; ++i) {
    int idx = i * 256 + t;
    int e = idx >> 4, c4 = (idx & 15) << 2;
    *(float4*)&dst[e * 64 + c4] = *(const float4*)&smf[e * 64 + c4];
  }
}

// combine 8 fp32 partials -> kvT bf16 [bh][e][d]
__global__ void kvc_kernel(const float* __restrict__ kvp, short* __restrict__ kvT) {
  int bh = blockIdx.x, t = threadIdx.x;
  const float* p0 = kvp + (size_t)bh * 8 * 4096;
  for (int rep = 0; rep < 4; ++rep) {
    int idx = rep * 1024 + t * 4;
    float4 s = *(const float4*)&p0[idx];
    for (int j = 1; j < 8; ++j) {
      float4 aa = *(const float4*)&p0[j * 4096 + idx];
      s.x += aa.x; s.y += aa.y; s.z += aa.z; s.w += aa.w;
    }
    short4 o;
    o.x = f2bf(s.x); o.y = f2bf(s.y); o.z = f2bf(s.z); o.w = f2bf(s.w);
    *(short4*)&kvT[(size_t)bh * 4096 + idx] = o;
  }
}

// ---------------- 4. out = (q @ kv) / z ----------------
__global__ __launch_bounds__(256, 2) void attn_kernel(const short* __restrict__ q,
                                                      const short* __restrict__ kvT,
                                                      const float* __restrict__ ksum,
                                                      short* __restrict__ attn) {
  int rb = blockIdx.x, bh = blockIdx.y;
  int b = bh >> 4, h = bh & 15;
  __shared__ float sks[64];
  __shared__ __align__(16) short satt[64 * 64];
  int t = threadIdx.x, w = t >> 6, lane = t & 63, rl = lane & 15, kg = lane >> 4;
  if (t < 64) sks[t] = ksum[bh * 64 + t];
  __syncthreads();
  int row0 = rb * 64 + w * 16;
  const short* qb = q + ((size_t)bh * Nn + row0) * DHd;
  const short* kvb = kvT + (size_t)bh * 4096;
  f32x4 acc[4] = {};
  float zp = 0.f;
  for (int kk = 0; kk < 2; ++kk) {
    int kb = kk * 32 + kg * 8;
    bf16x8 av = *(const bf16x8*)&qb[rl * DHd + kb];
    for (int jj = 0; jj < 8; ++jj) zp += bf2f(av[jj]) * sks[kb + jj];
    for (int nt = 0; nt < 4; ++nt) {
      bf16x8 bfr = *(const bf16x8*)&kvb[(nt * 16 + rl) * 64 + kb];
      acc[nt] = __builtin_amdgcn_mfma_f32_16x16x32_bf16(av, bfr, acc[nt], 0, 0, 0);
    }
  }
  zp += __shfl_xor(zp, 16);
  zp += __shfl_xor(zp, 32);     // every lane now holds z for row (lane&15)
  float zr[4];
  for (int r = 0; r < 4; ++r) zr[r] = __shfl(zp, kg * 4 + r);
  for (int nt = 0; nt < 4; ++nt)
    for (int r = 0; r < 4; ++r)
      satt[(w * 16 + kg * 4 + r) * 64 + nt * 16 + rl] = f2bf(acc[nt][r] / (zr[r] + 1e-6f));
  __syncthreads();
  for (int i = 0; i < 2; ++i) {
    int idx = i * 256 + t;                 // int4 index over 64x64 shorts
    int row = idx >> 3, c8 = (idx & 7) << 3;
    int n = rb * 64 + row;
    *(int4*)&attn[((size_t)(b * Nn + n)) * 1024 + h * 64 + c8] = *(const int4*)&satt[row * 64 + c8];
  }
}

// ---------------- launch ----------------
extern "C" void kernel_launch(void* const* d_in, const int* in_sizes, int n_in,
                              void* d_out, int out_size, void* d_ws, size_t ws_size,
                              hipStream_t stream) {
  const float* x  = (const float*)d_in[0];
  const float* Wq = (const float*)d_in[1];
  const float* Wk = (const float*)d_in[2];
  const float* Wv = (const float*)d_in[3];
  const float* Wo = (const float*)d_in[4];
  const float* bo = (const float*)d_in[5];
  float* out = (float*)d_out;

  char* ws = (char*)d_ws;
  size_t off = 0;
  auto alloc = [&](size_t bytes) {
    char* p = ws + off;
    off += (bytes + 255) & ~(size_t)255;
    return p;
  };
  short* xb   = (short*)alloc((size_t)Mrows * 1024 * 2);     // 32 MB
  short* Wt   = (short*)alloc((size_t)3072 * 1024 * 2);      // 6 MB
  short* WoT  = (short*)alloc((size_t)1024 * 1024 * 2);      // 2 MB
  short* qb   = (short*)alloc((size_t)64 * Nn * DHd * 2);    // 32 MB  [bh][n][d]
  short* kT   = (short*)alloc((size_t)64 * DHd * Nn * 2);    // 32 MB  [bh][d][n]
  short* vT   = (short*)alloc((size_t)64 * DHd * Nn * 2);    // 32 MB  [bh][d][n]
  float* ksum = (float*)alloc((size_t)64 * 64 * 4);          // fused ksum accumulator
  float* kvp  = (float*)alloc((size_t)64 * 8 * 4096 * 4);    // 8 MB kv partials
  short* kvT  = (short*)alloc((size_t)64 * 4096 * 2);        // [bh][e][d]
  short* attn = (short*)alloc((size_t)Mrows * 1024 * 2);     // 32 MB

  prep_kernel<<<dim3(64, 16, 5), 256, 0, stream>>>(x, Wq, Wk, Wv, Wo, xb, Wt, WoT, ksum);

  gemm128_kernel<0><<<3072, 256, 0, stream>>>(xb, Wt, qb, kT, vT, nullptr, nullptr, ksum, 24);
  kv_kernel<<<dim3(64, 8), 256, 0, stream>>>(kT, vT, kvp);
  kvc_kernel<<<64, 256, 0, stream>>>(kvp, kvT);
  attn_kernel<<<dim3(64, 64), 256, 0, stream>>>(qb, kvT, ksum, attn);
  gemm128_kernel<1><<<1024, 256, 0, stream>>>(attn, WoT, nullptr, nullptr, nullptr, out, bo, nullptr, 8);
}